// Round 4
// baseline (2099.404 us; speedup 1.0000x reference)
//
#include <hip/hip_runtime.h>
#include <math.h>

#define BB 32
#define NN 1000
#define CC 128
#define FF 128
#define OO 64
#define CAP 128
#define NB 40

// exact replica of JAX's np.float32(1.0 - 0.8) = 0.20000000298023224f
#define RMC ((float)(1.0 - 0.8))

// ---------------- pre: init mask/gate/ncur/pnorm + transpose the three W's ----------------
__global__ void k_pre(const float* __restrict__ mask, const int* __restrict__ Nn,
                      const float* __restrict__ p0, const float* __restrict__ p1,
                      const float* __restrict__ W0, const float* __restrict__ W1,
                      const float* __restrict__ W2,
                      float* __restrict__ m, int* __restrict__ ncur0,
                      float* __restrict__ pn, float* __restrict__ gate,
                      float* __restrict__ Wt){
  int blk = blockIdx.x, tid = threadIdx.x;
  if (blk == 3){
    for (int i = tid; i < BB*NN; i += 256){ float v = mask[i]; m[i] = v; gate[i] = v; }
    if (tid < BB) ncur0[tid] = Nn[tid];
    if (tid == 64){ float s=0.f; for(int c=0;c<FF;c++) s += p0[c]*p0[c]; pn[0] = sqrtf(s); }
    if (tid == 65){ float s=0.f; for(int c=0;c<FF;c++) s += p1[c]*p1[c]; pn[1] = sqrtf(s); }
  } else {
    const float* W = (blk == 0) ? W0 : (blk == 1) ? W1 : W2;
    float* T = Wt + (size_t)blk*FF*CC;
    for (int e = tid; e < FF*CC; e += 256){
      int c = e >> 7, f = e & 127;
      T[e] = W[f*CC + c];
    }
  }
}

// ---------------- CSR build (A is 0/1, symmetric, pre-masked), float4 scan ----------------
__global__ void k_csr(const float* __restrict__ A, short* __restrict__ idx,
                      int* __restrict__ cnt){
  int i = blockIdx.x, b = blockIdx.y, lane = threadIdx.x;   // block = 64 (one wave)
  const float4* row = (const float4*)(A + ((size_t)b*NN + i)*NN);
  short* out = idx + ((size_t)b*NN + i)*CAP;
  int count = 0;
  for (int base = 0; base < 250; base += 64){               // 1000 = 250 float4
    int q = base + lane;
    float4 v;
    if (q < 250) v = row[q]; else { v.x=v.y=v.z=v.w=0.f; }
    int lc = (v.x!=0.f) + (v.y!=0.f) + (v.z!=0.f) + (v.w!=0.f);
    int pre = lc;
    #pragma unroll
    for (int off = 1; off < 64; off <<= 1){
      int t = __shfl_up(pre, off);
      if (lane >= off) pre += t;
    }
    int tot = __shfl(pre, 63);
    pre -= lc;                                              // exclusive prefix
    int slot = count + pre;
    int j = q*4;
    if (v.x!=0.f && slot < CAP) out[slot++] = (short)j;
    if (v.y!=0.f && slot < CAP) out[slot++] = (short)(j+1);
    if (v.z!=0.f && slot < CAP) out[slot++] = (short)(j+2);
    if (v.w!=0.f && slot < CAP) out[slot++] = (short)(j+3);
    count += tot;
  }
  if (lane == 0) cnt[b*NN + i] = (count < CAP) ? count : CAP;
}

// ---------------- degree -> D = (1 + sum_nbr m_j + 1e-5)^-1/2 ----------------
__global__ void k_deg(const short* __restrict__ idx, const int* __restrict__ cnt,
                      const float* __restrict__ m, float* __restrict__ D){
  __shared__ float ml[NN];
  int b = blockIdx.y, tid = threadIdx.x;   // grid (4, BB), block = 256
  for (int i = tid; i < NN; i += 256) ml[i] = m[b*NN + i];
  __syncthreads();
  int j = blockIdx.x*250 + tid;
  if (tid < 250){
    const short* r = idx + ((size_t)b*NN + j)*CAP;
    int n = cnt[b*NN + j];
    float s0=0.f, s1=0.f, s2=0.f, s3=0.f;
    int k = 0;
    for (; k+4 <= n; k += 4){
      s0 += ml[r[k]]; s1 += ml[r[k+1]]; s2 += ml[r[k+2]]; s3 += ml[r[k+3]];
    }
    for (; k < n; k++) s0 += ml[r[k]];
    D[b*NN + j] = 1.0f / sqrtf(((s0+s1)+(s2+s3)) + 1.0f + 1e-5f);
  }
}

// ---- fused stage: gather(D*gate*h) -> t = D*(m*Y)+D^2*(g*h) -> GEMM -> relu*m -> [score] ----
template<bool SCORE>
__global__ void k_stage(const short* __restrict__ idx, const int* __restrict__ cnt,
                        const float* __restrict__ Dv, const float* __restrict__ m,
                        const float* __restrict__ gate,
                        const float* __restrict__ h,    // prev features [B,N,C]
                        const float* __restrict__ Wt,   // [cc][f] transposed
                        const float* __restrict__ bias,
                        const float* __restrict__ p, const float* __restrict__ pn,
                        float* __restrict__ Hout, float* __restrict__ ysc){
  __shared__ float dg[NN];            // D*gate for all nodes of this b (4 KB)
  __shared__ short nbl[NB][CAP];      // neighbor lists for our 40 nodes (10 KB)
  __shared__ int   cnl[NB];
  __shared__ float Dl[NB], ml[NB], gl[NB];
  __shared__ float t[NB][CC];         // 20.5 KB
  int b = blockIdx.y, tid = threadIdx.x;   // block = 256
  int i0 = blockIdx.x * NB;
  for (int j = tid; j < NN; j += 256)
    dg[j] = Dv[b*NN + j] * gate[b*NN + j];
  {  // coalesced copy of 40 idx rows (40*128 shorts = 10 KB)
    const uint* gsrc = (const uint*)(idx + ((size_t)b*NN + i0)*CAP);
    uint* ldst = (uint*)&nbl[0][0];
    for (int e = tid; e < NB*CAP/2; e += 256) ldst[e] = gsrc[e];
  }
  if (tid < NB){
    cnl[tid] = cnt[b*NN + i0 + tid];
    Dl[tid]  = Dv[b*NN + i0 + tid];
    ml[tid]  = m[b*NN + i0 + tid];
    gl[tid]  = gate[b*NN + i0 + tid];
  }
  __syncthreads();
  int sub = tid >> 7, c = tid & 127;
  const float* hb = h + (size_t)b*NN*CC;
  for (int s = 0; s < NB; s += 2){
    int ii = s + sub;                 // local node 0..39 (wave-uniform)
    int n = cnl[ii];
    float a0=0.f, a1=0.f, a2=0.f, a3=0.f;
    int k = 0;
    for (; k+4 <= n; k += 4){
      int j0=nbl[ii][k], j1=nbl[ii][k+1], j2=nbl[ii][k+2], j3=nbl[ii][k+3];
      float d0=dg[j0], d1=dg[j1], d2=dg[j2], d3=dg[j3];
      if (d0!=0.f) a0 += d0*hb[(size_t)j0*CC + c];
      if (d1!=0.f) a1 += d1*hb[(size_t)j1*CC + c];
      if (d2!=0.f) a2 += d2*hb[(size_t)j2*CC + c];
      if (d3!=0.f) a3 += d3*hb[(size_t)j3*CC + c];
    }
    for (; k < n; k++){
      int j = nbl[ii][k]; float d = dg[j];
      if (d!=0.f) a0 += d*hb[(size_t)j*CC + c];
    }
    float Y = (a0+a1)+(a2+a3);
    float Di = Dl[ii];
    t[ii][c] = Di*(ml[ii]*Y) + Di*Di*(gl[ii]*hb[(size_t)(i0+ii)*CC + c]);
  }
  __syncthreads();
  // ---- GEMM: 40x128 tile times Wt[128][128] ----
  int fg = tid & 31;                  // 4 consecutive f per thread
  int nr = tid >> 5;                  // 0..7 node-row
  float acc[5][4];
  float4 bi = ((const float4*)bias)[fg];
  #pragma unroll
  for (int n5 = 0; n5 < 5; n5++){
    acc[n5][0]=bi.x; acc[n5][1]=bi.y; acc[n5][2]=bi.z; acc[n5][3]=bi.w;
  }
  for (int c4 = 0; c4 < 32; c4++){
    float4 tv[5];
    #pragma unroll
    for (int n5 = 0; n5 < 5; n5++)
      tv[n5] = *((const float4*)&t[nr + n5*8][c4*4]);
    #pragma unroll
    for (int k = 0; k < 4; k++){
      float4 wv = ((const float4*)Wt)[(size_t)(c4*4 + k)*32 + fg];
      #pragma unroll
      for (int n5 = 0; n5 < 5; n5++){
        float tvv = (k==0) ? tv[n5].x : (k==1) ? tv[n5].y : (k==2) ? tv[n5].z : tv[n5].w;
        acc[n5][0] += tvv*wv.x; acc[n5][1] += tvv*wv.y;
        acc[n5][2] += tvv*wv.z; acc[n5][3] += tvv*wv.w;
      }
    }
  }
  float4 p4;
  if (SCORE) p4 = ((const float4*)p)[fg];
  #pragma unroll
  for (int n5 = 0; n5 < 5; n5++){
    int il = nr + n5*8;
    int i = i0 + il;
    float mi = ml[il];
    float4 o4;
    o4.x = fmaxf(acc[n5][0], 0.f)*mi;
    o4.y = fmaxf(acc[n5][1], 0.f)*mi;
    o4.z = fmaxf(acc[n5][2], 0.f)*mi;
    o4.w = fmaxf(acc[n5][3], 0.f)*mi;
    ((float4*)&Hout[((size_t)b*NN + i)*CC])[fg] = o4;
    if (SCORE){
      float s = o4.x*p4.x + o4.y*p4.y + o4.z*p4.z + o4.w*p4.w;
      s += __shfl_xor(s, 16);
      s += __shfl_xor(s, 8);
      s += __shfl_xor(s, 4);
      s += __shfl_xor(s, 2);
      s += __shfl_xor(s, 1);
      if (fg == 0) ysc[b*NN + i] = s / pn[0];
    }
  }
}

// ---------------- top-k pool: 1 node/thread, float4 LDS scan, ping-pong ncur ----------------
__global__ void k_pool(const float* __restrict__ y, float* __restrict__ m,
                       const int* __restrict__ ncur_in, int* __restrict__ ncur_out,
                       float* __restrict__ gate){
  __shared__ float yk[NN];
  int b = blockIdx.y, tid = threadIdx.x;   // grid (4, BB), block = 256
  int i = blockIdx.x*256 + tid;
  for (int j = tid; j < NN; j += 256)
    yk[j] = (m[b*NN + j] > 0.f) ? y[b*NN + j] : INFINITY;
  __syncthreads();
  int n = ncur_in[b];
  int nr = (int)((float)n * RMC);          // exact JAX semantics (f32 mult, trunc)
  float myv = (i < NN) ? yk[i] : INFINITY;
  int cnt = 0;
  const float4* yk4 = (const float4*)yk;   // broadcast reads: conflict-free
  #pragma unroll 5
  for (int q = 0; q < 250; q++){
    float4 v = yk4[q];
    int j0 = q*4;
    cnt += (int)((v.x < myv) || (v.x == myv && j0     < i));
    cnt += (int)((v.y < myv) || (v.y == myv && j0 + 1 < i));
    cnt += (int)((v.z < myv) || (v.z == myv && j0 + 2 < i));
    cnt += (int)((v.w < myv) || (v.w == myv && j0 + 3 < i));
  }
  if (i < NN){
    bool keep = (cnt >= nr) && (m[b*NN + i] > 0.f);
    m[b*NN + i]    = keep ? 1.0f : 0.0f;
    gate[b*NN + i] = keep ? tanhf(y[b*NN + i]) : 0.0f;
  }
  if (blockIdx.x == 0 && tid == 0) ncur_out[b] = n - nr;
}

// ---------------- global max pool + FC ----------------
__global__ void k_final(const float* __restrict__ H, const float* __restrict__ Wfc,
                        const float* __restrict__ bfc, float* __restrict__ out){
  __shared__ float red[4][FF];
  __shared__ float g[FF];
  int b = blockIdx.x, tid = threadIdx.x;   // block = 512
  int sub = tid >> 7, c = tid & 127;
  float mx = -INFINITY;
  for (int i = sub; i < NN; i += 4) mx = fmaxf(mx, H[((size_t)b*NN + i)*CC + c]);
  red[sub][c] = mx;
  __syncthreads();
  if (tid < FF) g[tid] = fmaxf(fmaxf(red[0][tid], red[1][tid]),
                               fmaxf(red[2][tid], red[3][tid]));
  __syncthreads();
  if (tid < OO){
    float acc = bfc[tid];
    for (int c2 = 0; c2 < FF; c2++) acc += g[c2]*Wfc[tid*FF + c2];
    out[b*OO + tid] = acc;
  }
}

extern "C" void kernel_launch(void* const* d_in, const int* in_sizes, int n_in,
                              void* d_out, int out_size, void* d_ws, size_t ws_size,
                              hipStream_t stream) {
  const float* x    = (const float*)d_in[0];
  const float* A    = (const float*)d_in[1];
  const float* mask = (const float*)d_in[2];
  const int*   Nn   = (const int*)  d_in[3];
  const float* W0   = (const float*)d_in[4];
  const float* b0   = (const float*)d_in[5];
  const float* W1   = (const float*)d_in[6];
  const float* b1   = (const float*)d_in[7];
  const float* W2   = (const float*)d_in[8];
  const float* b2   = (const float*)d_in[9];
  const float* p0   = (const float*)d_in[10];
  const float* p1   = (const float*)d_in[11];
  const float* Wfc  = (const float*)d_in[12];
  const float* bfc  = (const float*)d_in[13];
  float* out = (float*)d_out;

  // workspace carve
  char* w = (char*)d_ws;
  float* HA  = (float*)w; w += (size_t)BB*NN*CC*4;      // 16.38 MB
  float* HB  = (float*)w; w += (size_t)BB*NN*CC*4;      // 16.38 MB
  short* idx = (short*)w; w += (size_t)BB*NN*CAP*2;     // 8.19 MB
  float* Wt  = (float*)w; w += (size_t)3*FF*CC*4;       // 192 KB
  int*   cnt = (int*)w;   w += (size_t)BB*NN*4;
  float* D   = (float*)w; w += (size_t)BB*NN*4;
  float* m   = (float*)w; w += (size_t)BB*NN*4;
  float* ysc = (float*)w; w += (size_t)BB*NN*4;
  float* gate= (float*)w; w += (size_t)BB*NN*4;
  int*   ncur= (int*)w;   w += 3*BB*sizeof(int);        // ping-pong slots
  float* pn  = (float*)w; w += 64;

  k_pre<<<4, 256, 0, stream>>>(mask, Nn, p0, p1, W0, W1, W2, m, ncur, pn, gate, Wt);
  k_csr<<<dim3(NN, BB), 64, 0, stream>>>(A, idx, cnt);

  // ---- stage 1: x -> HA ----
  k_deg<<<dim3(4, BB), 256, 0, stream>>>(idx, cnt, m, D);
  k_stage<true><<<dim3(25, BB), 256, 0, stream>>>(idx, cnt, D, m, gate, x,
                                                  Wt + 0*FF*CC, b0, p0, pn + 0, HA, ysc);
  k_pool<<<dim3(4, BB), 256, 0, stream>>>(ysc, m, ncur + 0*BB, ncur + 1*BB, gate);

  // ---- stage 2: HA -> HB ----
  k_deg<<<dim3(4, BB), 256, 0, stream>>>(idx, cnt, m, D);
  k_stage<true><<<dim3(25, BB), 256, 0, stream>>>(idx, cnt, D, m, gate, HA,
                                                  Wt + 1*FF*CC, b1, p1, pn + 1, HB, ysc);
  k_pool<<<dim3(4, BB), 256, 0, stream>>>(ysc, m, ncur + 1*BB, ncur + 2*BB, gate);

  // ---- stage 3: HB -> HA ----
  k_deg<<<dim3(4, BB), 256, 0, stream>>>(idx, cnt, m, D);
  k_stage<false><<<dim3(25, BB), 256, 0, stream>>>(idx, cnt, D, m, gate, HB,
                                                   Wt + 2*FF*CC, b2, nullptr, nullptr, HA, ysc);

  // ---- global max pool + FC ----
  k_final<<<BB, 512, 0, stream>>>(HA, Wfc, bfc, out);
}

// Round 5
// 1644.802 us; speedup vs baseline: 1.2764x; 1.2764x over previous
//
#include <hip/hip_runtime.h>
#include <math.h>

#define BB 32
#define NN 1000
#define CC 128
#define FF 128
#define OO 64
#define CAP 128
#define NB 40

// exact replica of JAX's np.float32(1.0 - 0.8) = 0.20000000298023224f
#define RMC ((float)(1.0 - 0.8))

// ---------------- pre: init mask/gate/ncur/pnorm + transpose the three W's ----------------
__global__ void k_pre(const float* __restrict__ mask, const int* __restrict__ Nn,
                      const float* __restrict__ p0, const float* __restrict__ p1,
                      const float* __restrict__ W0, const float* __restrict__ W1,
                      const float* __restrict__ W2,
                      float* __restrict__ m, int* __restrict__ ncur0,
                      float* __restrict__ pn, float* __restrict__ gate,
                      float* __restrict__ Wt){
  int blk = blockIdx.x, tid = threadIdx.x;
  if (blk == 3){
    for (int i = tid; i < BB*NN; i += 256){ float v = mask[i]; m[i] = v; gate[i] = v; }
    if (tid < BB) ncur0[tid] = Nn[tid];
    if (tid == 64){ float s=0.f; for(int c=0;c<FF;c++) s += p0[c]*p0[c]; pn[0] = sqrtf(s); }
    if (tid == 65){ float s=0.f; for(int c=0;c<FF;c++) s += p1[c]*p1[c]; pn[1] = sqrtf(s); }
  } else {
    const float* W = (blk == 0) ? W0 : (blk == 1) ? W1 : W2;
    float* T = Wt + (size_t)blk*FF*CC;
    for (int e = tid; e < FF*CC; e += 256){
      int c = e >> 7, f = e & 127;
      T[e] = W[f*CC + c];
    }
  }
}

// ---------------- CSR build (A is 0/1, symmetric, pre-masked), float4 scan ----------------
__global__ void k_csr(const float* __restrict__ A, short* __restrict__ idx,
                      int* __restrict__ cnt){
  int i = blockIdx.x, b = blockIdx.y, lane = threadIdx.x;   // block = 64 (one wave)
  const float4* row = (const float4*)(A + ((size_t)b*NN + i)*NN);
  short* out = idx + ((size_t)b*NN + i)*CAP;
  int count = 0;
  for (int base = 0; base < 250; base += 64){               // 1000 = 250 float4
    int q = base + lane;
    float4 v;
    if (q < 250) v = row[q]; else { v.x=v.y=v.z=v.w=0.f; }
    int lc = (v.x!=0.f) + (v.y!=0.f) + (v.z!=0.f) + (v.w!=0.f);
    int pre = lc;
    #pragma unroll
    for (int off = 1; off < 64; off <<= 1){
      int t = __shfl_up(pre, off);
      if (lane >= off) pre += t;
    }
    int tot = __shfl(pre, 63);
    pre -= lc;                                              // exclusive prefix
    int slot = count + pre;
    int j = q*4;
    if (v.x!=0.f && slot < CAP) out[slot++] = (short)j;
    if (v.y!=0.f && slot < CAP) out[slot++] = (short)(j+1);
    if (v.z!=0.f && slot < CAP) out[slot++] = (short)(j+2);
    if (v.w!=0.f && slot < CAP) out[slot++] = (short)(j+3);
    count += tot;
  }
  if (lane == 0) cnt[b*NN + i] = (count < CAP) ? count : CAP;
}

// ---------------- degree -> D = (1 + sum_nbr m_j + 1e-5)^-1/2 ----------------
__global__ void k_deg(const short* __restrict__ idx, const int* __restrict__ cnt,
                      const float* __restrict__ m, float* __restrict__ D){
  __shared__ float ml[NN];
  int b = blockIdx.y, tid = threadIdx.x;   // grid (4, BB), block = 256
  for (int i = tid; i < NN; i += 256) ml[i] = m[b*NN + i];
  __syncthreads();
  int j = blockIdx.x*250 + tid;
  if (tid < 250){
    const short* r = idx + ((size_t)b*NN + j)*CAP;
    int n = cnt[b*NN + j];
    float s0=0.f, s1=0.f, s2=0.f, s3=0.f;
    int k = 0;
    for (; k+4 <= n; k += 4){
      s0 += ml[r[k]]; s1 += ml[r[k+1]]; s2 += ml[r[k+2]]; s3 += ml[r[k+3]];
    }
    for (; k < n; k++) s0 += ml[r[k]];
    D[b*NN + j] = 1.0f / sqrtf(((s0+s1)+(s2+s3)) + 1.0f + 1e-5f);
  }
}

// ---------------- Y_i = sum_{j in nbr(i)} D_j*gate_j*h_j  (dead rows/edges skipped) ----------------
__global__ void k_agg(const short* __restrict__ idx, const int* __restrict__ cnt,
                      const float* __restrict__ D, const float* __restrict__ gate,
                      const float* __restrict__ m,
                      const float* __restrict__ h, float* __restrict__ Y){
  __shared__ short nb[CAP];
  __shared__ float dn[CAP];
  int blk = blockIdx.x;                    // XCD swizzle: same b lands on same XCD
  int b = (blk & 7) + 8*((blk >> 3) & 3);
  int i = blk >> 5;
  if (m[b*NN + i] == 0.f) return;          // masked target: Y never used (x * m_i = 0)
  int c = threadIdx.x;                     // block = 128
  int n = cnt[b*NN + i];
  const short* r = idx + ((size_t)b*NN + i)*CAP;
  for (int k = c; k < n; k += 128){
    int j = r[k];
    nb[k] = (short)j;
    dn[k] = D[b*NN + j] * gate[b*NN + j];
  }
  __syncthreads();
  float a0=0.f, a1=0.f, a2=0.f, a3=0.f;
  const float* hb = h + (size_t)b*NN*CC;
  int k = 0;
  for (; k+4 <= n; k += 4){
    float d0=dn[k], d1=dn[k+1], d2=dn[k+2], d3=dn[k+3];
    if (d0!=0.f) a0 += d0*hb[(size_t)nb[k  ]*CC + c];
    if (d1!=0.f) a1 += d1*hb[(size_t)nb[k+1]*CC + c];
    if (d2!=0.f) a2 += d2*hb[(size_t)nb[k+2]*CC + c];
    if (d3!=0.f) a3 += d3*hb[(size_t)nb[k+3]*CC + c];
  }
  for (; k < n; k++){
    float d = dn[k];
    if (d!=0.f) a0 += d*hb[(size_t)nb[k]*CC + c];
  }
  Y[((size_t)b*NN + i)*CC + c] = (a0+a1)+(a2+a3);
}

// ---- t = D*(m*Y) + D^2*(gate*h) ; H = relu(t @ W^T + b)*m ; optional fused score ----
template<bool SCORE>
__global__ void __launch_bounds__(256, 2)
k_lin(const float* __restrict__ Y, const float* __restrict__ h,
      const float* __restrict__ Dv, const float* __restrict__ m,
      const float* __restrict__ gate,
      const float* __restrict__ Wt,   // [cc][f] transposed
      const float* __restrict__ bias,
      const float* __restrict__ p, const float* __restrict__ pn,
      float* __restrict__ Hout, float* __restrict__ ysc){
  __shared__ float t[NB][CC];              // 20.5 KB
  __shared__ float ml[NB];
  int b = blockIdx.y, tid = threadIdx.x;   // block = 256
  int i0 = blockIdx.x * NB;
  if (tid < NB) ml[tid] = m[b*NN + i0 + tid];
  for (int e = tid; e < NB*CC; e += 256){
    int n = e >> 7, c = e & 127;
    int i = i0 + n;
    float Di = Dv[b*NN + i], mi = m[b*NN + i], gi = gate[b*NN + i];
    size_t o = ((size_t)b*NN + i)*CC + c;
    t[n][c] = Di*(mi*Y[o]) + Di*Di*(gi*h[o]);
  }
  __syncthreads();
  int fg = tid & 31;                       // 4 consecutive f per thread
  int nr = tid >> 5;                       // 0..7 node-row
  float acc[5][4];
  float4 bi = ((const float4*)bias)[fg];
  #pragma unroll
  for (int n5 = 0; n5 < 5; n5++){
    acc[n5][0]=bi.x; acc[n5][1]=bi.y; acc[n5][2]=bi.z; acc[n5][3]=bi.w;
  }
  for (int c4 = 0; c4 < 32; c4++){
    float4 tv[5];
    #pragma unroll
    for (int n5 = 0; n5 < 5; n5++)
      tv[n5] = *((const float4*)&t[nr + n5*8][c4*4]);
    #pragma unroll
    for (int k = 0; k < 4; k++){
      float4 wv = ((const float4*)Wt)[(size_t)(c4*4 + k)*32 + fg];
      #pragma unroll
      for (int n5 = 0; n5 < 5; n5++){
        float tvv = (k==0) ? tv[n5].x : (k==1) ? tv[n5].y : (k==2) ? tv[n5].z : tv[n5].w;
        acc[n5][0] += tvv*wv.x; acc[n5][1] += tvv*wv.y;
        acc[n5][2] += tvv*wv.z; acc[n5][3] += tvv*wv.w;
      }
    }
  }
  float4 p4;
  if (SCORE) p4 = ((const float4*)p)[fg];
  #pragma unroll
  for (int n5 = 0; n5 < 5; n5++){
    int il = nr + n5*8;
    int i = i0 + il;
    float mi = ml[il];
    float4 o4;
    o4.x = fmaxf(acc[n5][0], 0.f)*mi;
    o4.y = fmaxf(acc[n5][1], 0.f)*mi;
    o4.z = fmaxf(acc[n5][2], 0.f)*mi;
    o4.w = fmaxf(acc[n5][3], 0.f)*mi;
    ((float4*)&Hout[((size_t)b*NN + i)*CC])[fg] = o4;
    if (SCORE){
      float s = o4.x*p4.x + o4.y*p4.y + o4.z*p4.z + o4.w*p4.w;
      s += __shfl_xor(s, 16);
      s += __shfl_xor(s, 8);
      s += __shfl_xor(s, 4);
      s += __shfl_xor(s, 2);
      s += __shfl_xor(s, 1);
      if (fg == 0) ysc[b*NN + i] = s / pn[0];
    }
  }
}

// ---------------- top-k pool: 1 node/thread, float4 LDS scan, ping-pong ncur ----------------
__global__ void k_pool(const float* __restrict__ y, float* __restrict__ m,
                       const int* __restrict__ ncur_in, int* __restrict__ ncur_out,
                       float* __restrict__ gate){
  __shared__ float yk[NN];
  int b = blockIdx.y, tid = threadIdx.x;   // grid (4, BB), block = 256
  int i = blockIdx.x*256 + tid;
  for (int j = tid; j < NN; j += 256)
    yk[j] = (m[b*NN + j] > 0.f) ? y[b*NN + j] : INFINITY;
  __syncthreads();
  int n = ncur_in[b];
  int nr = (int)((float)n * RMC);          // exact JAX semantics (f32 mult, trunc)
  float myv = (i < NN) ? yk[i] : INFINITY;
  int cnt = 0;
  const float4* yk4 = (const float4*)yk;   // broadcast reads: conflict-free
  #pragma unroll 5
  for (int q = 0; q < 250; q++){
    float4 v = yk4[q];
    int j0 = q*4;
    cnt += (int)((v.x < myv) || (v.x == myv && j0     < i));
    cnt += (int)((v.y < myv) || (v.y == myv && j0 + 1 < i));
    cnt += (int)((v.z < myv) || (v.z == myv && j0 + 2 < i));
    cnt += (int)((v.w < myv) || (v.w == myv && j0 + 3 < i));
  }
  if (i < NN){
    bool keep = (cnt >= nr) && (m[b*NN + i] > 0.f);
    m[b*NN + i]    = keep ? 1.0f : 0.0f;
    gate[b*NN + i] = keep ? tanhf(y[b*NN + i]) : 0.0f;
  }
  if (blockIdx.x == 0 && tid == 0) ncur_out[b] = n - nr;
}

// ---------------- partial global max pool (masked rows skipped; relu => max>=0) ----------------
__global__ void k_fmax(const float* __restrict__ H, const float* __restrict__ m,
                       float* __restrict__ part){
  int sx = blockIdx.x, b = blockIdx.y, c = threadIdx.x;   // grid (8, BB), block = 128
  float mx = 0.f;
  int i0 = sx*125;
  for (int i = i0; i < i0+125; i++){
    if (m[b*NN + i] != 0.f)
      mx = fmaxf(mx, H[((size_t)b*NN + i)*CC + c]);
  }
  part[((size_t)b*8 + sx)*CC + c] = mx;
}

// ---------------- combine partial maxima + FC ----------------
__global__ void k_fc(const float* __restrict__ part, const float* __restrict__ Wfc,
                     const float* __restrict__ bfc, float* __restrict__ out){
  __shared__ float g[FF];
  int b = blockIdx.x, tid = threadIdx.x;   // block = 128
  float mx = 0.f;
  #pragma unroll
  for (int s = 0; s < 8; s++) mx = fmaxf(mx, part[((size_t)b*8 + s)*CC + tid]);
  g[tid] = mx;
  __syncthreads();
  if (tid < OO){
    float acc = bfc[tid];
    for (int c = 0; c < FF; c++) acc += g[c]*Wfc[tid*FF + c];
    out[b*OO + tid] = acc;
  }
}

extern "C" void kernel_launch(void* const* d_in, const int* in_sizes, int n_in,
                              void* d_out, int out_size, void* d_ws, size_t ws_size,
                              hipStream_t stream) {
  const float* x    = (const float*)d_in[0];
  const float* A    = (const float*)d_in[1];
  const float* mask = (const float*)d_in[2];
  const int*   Nn   = (const int*)  d_in[3];
  const float* W0   = (const float*)d_in[4];
  const float* b0   = (const float*)d_in[5];
  const float* W1   = (const float*)d_in[6];
  const float* b1   = (const float*)d_in[7];
  const float* W2   = (const float*)d_in[8];
  const float* b2   = (const float*)d_in[9];
  const float* p0   = (const float*)d_in[10];
  const float* p1   = (const float*)d_in[11];
  const float* Wfc  = (const float*)d_in[12];
  const float* bfc  = (const float*)d_in[13];
  float* out = (float*)d_out;

  // workspace carve (~42 MB)
  char* w = (char*)d_ws;
  float* H   = (float*)w; w += (size_t)BB*NN*CC*4;      // 16.38 MB
  float* Yb  = (float*)w; w += (size_t)BB*NN*CC*4;      // 16.38 MB
  short* idx = (short*)w; w += (size_t)BB*NN*CAP*2;     // 8.19 MB
  float* Wt  = (float*)w; w += (size_t)3*FF*CC*4;       // 192 KB
  float* part= (float*)w; w += (size_t)8*BB*CC*4;       // 131 KB
  int*   cnt = (int*)w;   w += (size_t)BB*NN*4;
  float* D   = (float*)w; w += (size_t)BB*NN*4;
  float* m   = (float*)w; w += (size_t)BB*NN*4;
  float* ysc = (float*)w; w += (size_t)BB*NN*4;
  float* gate= (float*)w; w += (size_t)BB*NN*4;
  int*   ncur= (int*)w;   w += 3*BB*sizeof(int);        // ping-pong slots
  float* pn  = (float*)w; w += 64;

  k_pre<<<4, 256, 0, stream>>>(mask, Nn, p0, p1, W0, W1, W2, m, ncur, pn, gate, Wt);
  k_csr<<<dim3(NN, BB), 64, 0, stream>>>(A, idx, cnt);

  // ---- stage 1: x -> H ----
  k_deg<<<dim3(4, BB), 256, 0, stream>>>(idx, cnt, m, D);
  k_agg<<<BB*NN, 128, 0, stream>>>(idx, cnt, D, gate, m, x, Yb);
  k_lin<true><<<dim3(25, BB), 256, 0, stream>>>(Yb, x, D, m, gate, Wt + 0*FF*CC, b0,
                                                p0, pn + 0, H, ysc);
  k_pool<<<dim3(4, BB), 256, 0, stream>>>(ysc, m, ncur + 0*BB, ncur + 1*BB, gate);

  // ---- stage 2: H -> H (in-place safe: each block reads only rows it writes) ----
  k_deg<<<dim3(4, BB), 256, 0, stream>>>(idx, cnt, m, D);
  k_agg<<<BB*NN, 128, 0, stream>>>(idx, cnt, D, gate, m, H, Yb);
  k_lin<true><<<dim3(25, BB), 256, 0, stream>>>(Yb, H, D, m, gate, Wt + 1*FF*CC, b1,
                                                p1, pn + 1, H, ysc);
  k_pool<<<dim3(4, BB), 256, 0, stream>>>(ysc, m, ncur + 1*BB, ncur + 2*BB, gate);

  // ---- stage 3: H -> H ----
  k_deg<<<dim3(4, BB), 256, 0, stream>>>(idx, cnt, m, D);
  k_agg<<<BB*NN, 128, 0, stream>>>(idx, cnt, D, gate, m, H, Yb);
  k_lin<false><<<dim3(25, BB), 256, 0, stream>>>(Yb, H, D, m, gate, Wt + 2*FF*CC, b2,
                                                 nullptr, nullptr, H, ysc);

  // ---- global max pool + FC ----
  k_fmax<<<dim3(8, BB), 128, 0, stream>>>(H, m, part);
  k_fc<<<BB, 128, 0, stream>>>(part, Wfc, bfc, out);
}

// Round 6
// 602.235 us; speedup vs baseline: 3.4860x; 2.7312x over previous
//
#include <hip/hip_runtime.h>
#include <math.h>

#define BB 32
#define NN 1000
#define CC 128
#define FF 128
#define OO 64
#define CAP 128
#define NB 40

// exact replica of JAX's np.float32(1.0 - 0.8) = 0.20000000298023224f
#define RMC ((float)(1.0 - 0.8))

// ---------------- pre: init mask/gate/ncur/pnorm + transpose the three W's ----------------
__global__ void k_pre(const float* __restrict__ mask, const int* __restrict__ Nn,
                      const float* __restrict__ p0, const float* __restrict__ p1,
                      const float* __restrict__ W0, const float* __restrict__ W1,
                      const float* __restrict__ W2,
                      float* __restrict__ m, int* __restrict__ ncur0,
                      float* __restrict__ pn, float* __restrict__ gate,
                      float* __restrict__ Wt){
  int blk = blockIdx.x, tid = threadIdx.x;
  if (blk == 3){
    for (int i = tid; i < BB*NN; i += 256){ float v = mask[i]; m[i] = v; gate[i] = v; }
    if (tid < BB) ncur0[tid] = Nn[tid];
    if (tid == 64){ float s=0.f; for(int c=0;c<FF;c++) s += p0[c]*p0[c]; pn[0] = sqrtf(s); }
    if (tid == 65){ float s=0.f; for(int c=0;c<FF;c++) s += p1[c]*p1[c]; pn[1] = sqrtf(s); }
  } else {
    const float* W = (blk == 0) ? W0 : (blk == 1) ? W1 : W2;
    float* T = Wt + (size_t)blk*FF*CC;
    for (int e = tid; e < FF*CC; e += 256){
      int c = e >> 7, f = e & 127;
      T[e] = W[f*CC + c];
    }
  }
}

// ---------------- CSR build (A is 0/1, symmetric, pre-masked), float4 scan ----------------
__global__ void k_csr(const float* __restrict__ A, short* __restrict__ idx,
                      int* __restrict__ cnt){
  int i = blockIdx.x, b = blockIdx.y, lane = threadIdx.x;   // block = 64 (one wave)
  const float4* row = (const float4*)(A + ((size_t)b*NN + i)*NN);
  short* out = idx + ((size_t)b*NN + i)*CAP;
  int count = 0;
  for (int base = 0; base < 250; base += 64){               // 1000 = 250 float4
    int q = base + lane;
    float4 v;
    if (q < 250) v = row[q]; else { v.x=v.y=v.z=v.w=0.f; }
    int lc = (v.x!=0.f) + (v.y!=0.f) + (v.z!=0.f) + (v.w!=0.f);
    int pre = lc;
    #pragma unroll
    for (int off = 1; off < 64; off <<= 1){
      int t = __shfl_up(pre, off);
      if (lane >= off) pre += t;
    }
    int tot = __shfl(pre, 63);
    pre -= lc;                                              // exclusive prefix
    int slot = count + pre;
    int j = q*4;
    if (v.x!=0.f && slot < CAP) out[slot++] = (short)j;
    if (v.y!=0.f && slot < CAP) out[slot++] = (short)(j+1);
    if (v.z!=0.f && slot < CAP) out[slot++] = (short)(j+2);
    if (v.w!=0.f && slot < CAP) out[slot++] = (short)(j+3);
    count += tot;
  }
  if (lane == 0) cnt[b*NN + i] = (count < CAP) ? count : CAP;
}

// ---------------- degree -> D = (1 + sum_nbr m_j + 1e-5)^-1/2 ----------------
__global__ void k_deg(const short* __restrict__ idx, const int* __restrict__ cnt,
                      const float* __restrict__ m, float* __restrict__ D){
  __shared__ float ml[NN];
  int b = blockIdx.y, tid = threadIdx.x;   // grid (4, BB), block = 256
  for (int i = tid; i < NN; i += 256) ml[i] = m[b*NN + i];
  __syncthreads();
  int j = blockIdx.x*250 + tid;
  if (tid < 250){
    const short* r = idx + ((size_t)b*NN + j)*CAP;
    int n = cnt[b*NN + j];
    float s0=0.f, s1=0.f, s2=0.f, s3=0.f;
    int k = 0;
    for (; k+4 <= n; k += 4){
      s0 += ml[r[k]]; s1 += ml[r[k+1]]; s2 += ml[r[k+2]]; s3 += ml[r[k+3]];
    }
    for (; k < n; k++) s0 += ml[r[k]];
    D[b*NN + j] = 1.0f / sqrtf(((s0+s1)+(s2+s3)) + 1.0f + 1e-5f);
  }
}

// ---------------- Y_i = sum_{j in nbr(i)} D_j*gate_j*h_j  (dead rows/edges skipped) ----------------
__global__ void k_agg(const short* __restrict__ idx, const int* __restrict__ cnt,
                      const float* __restrict__ D, const float* __restrict__ gate,
                      const float* __restrict__ m,
                      const float* __restrict__ h, float* __restrict__ Y){
  __shared__ short nb[CAP];
  __shared__ float dn[CAP];
  int blk = blockIdx.x;                    // XCD swizzle: same b lands on same XCD
  int b = (blk & 7) + 8*((blk >> 3) & 3);
  int i = blk >> 5;
  if (m[b*NN + i] == 0.f) return;          // masked target: Y never used (t *= m_i = 0)
  int c = threadIdx.x;                     // block = 128
  int n = cnt[b*NN + i];
  const short* r = idx + ((size_t)b*NN + i)*CAP;
  for (int k = c; k < n; k += 128){
    int j = r[k];
    nb[k] = (short)j;
    dn[k] = D[b*NN + j] * gate[b*NN + j];
  }
  __syncthreads();
  float a0=0.f, a1=0.f, a2=0.f, a3=0.f;
  const float* hb = h + (size_t)b*NN*CC;
  int k = 0;
  for (; k+4 <= n; k += 4){
    float d0=dn[k], d1=dn[k+1], d2=dn[k+2], d3=dn[k+3];
    if (d0!=0.f) a0 += d0*hb[(size_t)nb[k  ]*CC + c];
    if (d1!=0.f) a1 += d1*hb[(size_t)nb[k+1]*CC + c];
    if (d2!=0.f) a2 += d2*hb[(size_t)nb[k+2]*CC + c];
    if (d3!=0.f) a3 += d3*hb[(size_t)nb[k+3]*CC + c];
  }
  for (; k < n; k++){
    float d = dn[k];
    if (d!=0.f) a0 += d*hb[(size_t)nb[k]*CC + c];
  }
  Y[((size_t)b*NN + i)*CC + c] = (a0+a1)+(a2+a3);
}

// ---- t = D*(m*Y) + D^2*(gate*h) ; H = relu(t @ W^T + b)*m ----
// NOTE: exact R3 body. DO NOT add __launch_bounds__, epilogue fusion, or extra LDS:
// both decorated variants (R4 k_stage, R5 k_lin) crossed a VGPR occupancy step and
// spilled the hot loop (VGPR 64/128, ~1.5 GB phantom HBM traffic, ~590 µs vs <75 µs).
__global__ void k_lin(const float* __restrict__ Y, const float* __restrict__ h,
                      const float* __restrict__ Dv, const float* __restrict__ m,
                      const float* __restrict__ gate,
                      const float* __restrict__ Wt,   // [cc][f] transposed
                      const float* __restrict__ bias, float* __restrict__ Hout){
  __shared__ float t[NB][CC];              // 20.5 KB
  int b = blockIdx.y, tid = threadIdx.x;   // block = 256
  int i0 = blockIdx.x * NB;
  for (int e = tid; e < NB*CC; e += 256){
    int n = e >> 7, c = e & 127;
    int i = i0 + n;
    float Di = Dv[b*NN + i], mi = m[b*NN + i], gi = gate[b*NN + i];
    size_t o = ((size_t)b*NN + i)*CC + c;
    t[n][c] = Di*(mi*Y[o]) + Di*Di*(gi*h[o]);
  }
  __syncthreads();
  int fg = tid & 31;                       // 4 consecutive f per thread
  int nr = tid >> 5;                       // 0..7 node-row
  float acc[5][4];
  float4 bi = ((const float4*)bias)[fg];
  #pragma unroll
  for (int n5 = 0; n5 < 5; n5++){
    acc[n5][0]=bi.x; acc[n5][1]=bi.y; acc[n5][2]=bi.z; acc[n5][3]=bi.w;
  }
  for (int c4 = 0; c4 < 32; c4++){
    float4 tv[5];
    #pragma unroll
    for (int n5 = 0; n5 < 5; n5++)
      tv[n5] = *((const float4*)&t[nr + n5*8][c4*4]);
    #pragma unroll
    for (int k = 0; k < 4; k++){
      float4 wv = ((const float4*)Wt)[(size_t)(c4*4 + k)*32 + fg];
      #pragma unroll
      for (int n5 = 0; n5 < 5; n5++){
        float tvv = (k==0) ? tv[n5].x : (k==1) ? tv[n5].y : (k==2) ? tv[n5].z : tv[n5].w;
        acc[n5][0] += tvv*wv.x; acc[n5][1] += tvv*wv.y;
        acc[n5][2] += tvv*wv.z; acc[n5][3] += tvv*wv.w;
      }
    }
  }
  #pragma unroll
  for (int n5 = 0; n5 < 5; n5++){
    int i = i0 + nr + n5*8;
    float mi = m[b*NN + i];
    float4 o4;
    o4.x = fmaxf(acc[n5][0], 0.f)*mi;
    o4.y = fmaxf(acc[n5][1], 0.f)*mi;
    o4.z = fmaxf(acc[n5][2], 0.f)*mi;
    o4.w = fmaxf(acc[n5][3], 0.f)*mi;
    ((float4*)&Hout[((size_t)b*NN + i)*CC])[fg] = o4;
  }
}

// ---------------- pool scores y_i = (H_i . p) / |p| ----------------
__global__ void k_score(const float* __restrict__ H, const float* __restrict__ p,
                        const float* __restrict__ pn, float* __restrict__ y){
  int i = blockIdx.x, b = blockIdx.y, lane = threadIdx.x;  // block = 64
  const float* hrow = H + ((size_t)b*NN + i)*CC;
  float s = hrow[lane]*p[lane] + hrow[lane+64]*p[lane+64];
  for (int off = 32; off > 0; off >>= 1) s += __shfl_down(s, off);
  if (lane == 0) y[b*NN + i] = s / pn[0];
}

// ---------------- top-k pool: 1 node/thread, float4 LDS scan, ping-pong ncur ----------------
__global__ void k_pool(const float* __restrict__ y, float* __restrict__ m,
                       const int* __restrict__ ncur_in, int* __restrict__ ncur_out,
                       float* __restrict__ gate){
  __shared__ float yk[NN];
  int b = blockIdx.y, tid = threadIdx.x;   // grid (4, BB), block = 256
  int i = blockIdx.x*256 + tid;
  for (int j = tid; j < NN; j += 256)
    yk[j] = (m[b*NN + j] > 0.f) ? y[b*NN + j] : INFINITY;
  __syncthreads();
  int n = ncur_in[b];
  int nr = (int)((float)n * RMC);          // exact JAX semantics (f32 mult, trunc)
  float myv = (i < NN) ? yk[i] : INFINITY;
  int cnt = 0;
  const float4* yk4 = (const float4*)yk;   // broadcast reads: conflict-free
  #pragma unroll 5
  for (int q = 0; q < 250; q++){
    float4 v = yk4[q];
    int j0 = q*4;
    cnt += (int)((v.x < myv) || (v.x == myv && j0     < i));
    cnt += (int)((v.y < myv) || (v.y == myv && j0 + 1 < i));
    cnt += (int)((v.z < myv) || (v.z == myv && j0 + 2 < i));
    cnt += (int)((v.w < myv) || (v.w == myv && j0 + 3 < i));
  }
  if (i < NN){
    bool keep = (cnt >= nr) && (m[b*NN + i] > 0.f);
    m[b*NN + i]    = keep ? 1.0f : 0.0f;
    gate[b*NN + i] = keep ? tanhf(y[b*NN + i]) : 0.0f;
  }
  if (blockIdx.x == 0 && tid == 0) ncur_out[b] = n - nr;
}

// ---------------- partial global max pool (masked rows skipped; relu => max>=0) ----------------
__global__ void k_fmax(const float* __restrict__ H, const float* __restrict__ m,
                       float* __restrict__ part){
  int sx = blockIdx.x, b = blockIdx.y, c = threadIdx.x;   // grid (8, BB), block = 128
  float mx = 0.f;
  int i0 = sx*125;
  for (int i = i0; i < i0+125; i++){
    if (m[b*NN + i] != 0.f)
      mx = fmaxf(mx, H[((size_t)b*NN + i)*CC + c]);
  }
  part[((size_t)b*8 + sx)*CC + c] = mx;
}

// ---------------- combine partial maxima + FC ----------------
__global__ void k_fc(const float* __restrict__ part, const float* __restrict__ Wfc,
                     const float* __restrict__ bfc, float* __restrict__ out){
  __shared__ float g[FF];
  int b = blockIdx.x, tid = threadIdx.x;   // block = 128
  float mx = 0.f;
  #pragma unroll
  for (int s = 0; s < 8; s++) mx = fmaxf(mx, part[((size_t)b*8 + s)*CC + tid]);
  g[tid] = mx;
  __syncthreads();
  if (tid < OO){
    float acc = bfc[tid];
    for (int c = 0; c < FF; c++) acc += g[c]*Wfc[tid*FF + c];
    out[b*OO + tid] = acc;
  }
}

extern "C" void kernel_launch(void* const* d_in, const int* in_sizes, int n_in,
                              void* d_out, int out_size, void* d_ws, size_t ws_size,
                              hipStream_t stream) {
  const float* x    = (const float*)d_in[0];
  const float* A    = (const float*)d_in[1];
  const float* mask = (const float*)d_in[2];
  const int*   Nn   = (const int*)  d_in[3];
  const float* W0   = (const float*)d_in[4];
  const float* b0   = (const float*)d_in[5];
  const float* W1   = (const float*)d_in[6];
  const float* b1   = (const float*)d_in[7];
  const float* W2   = (const float*)d_in[8];
  const float* b2   = (const float*)d_in[9];
  const float* p0   = (const float*)d_in[10];
  const float* p1   = (const float*)d_in[11];
  const float* Wfc  = (const float*)d_in[12];
  const float* bfc  = (const float*)d_in[13];
  float* out = (float*)d_out;

  // workspace carve (~42 MB)
  char* w = (char*)d_ws;
  float* H   = (float*)w; w += (size_t)BB*NN*CC*4;      // 16.38 MB
  float* Yb  = (float*)w; w += (size_t)BB*NN*CC*4;      // 16.38 MB
  short* idx = (short*)w; w += (size_t)BB*NN*CAP*2;     // 8.19 MB
  float* Wt  = (float*)w; w += (size_t)3*FF*CC*4;       // 192 KB
  float* part= (float*)w; w += (size_t)8*BB*CC*4;       // 131 KB
  int*   cnt = (int*)w;   w += (size_t)BB*NN*4;
  float* D   = (float*)w; w += (size_t)BB*NN*4;
  float* m   = (float*)w; w += (size_t)BB*NN*4;
  float* ysc = (float*)w; w += (size_t)BB*NN*4;
  float* gate= (float*)w; w += (size_t)BB*NN*4;
  int*   ncur= (int*)w;   w += 3*BB*sizeof(int);        // ping-pong slots
  float* pn  = (float*)w; w += 64;

  k_pre<<<4, 256, 0, stream>>>(mask, Nn, p0, p1, W0, W1, W2, m, ncur, pn, gate, Wt);
  k_csr<<<dim3(NN, BB), 64, 0, stream>>>(A, idx, cnt);

  // ---- stage 1: x -> H ----
  k_deg<<<dim3(4, BB), 256, 0, stream>>>(idx, cnt, m, D);
  k_agg<<<BB*NN, 128, 0, stream>>>(idx, cnt, D, gate, m, x, Yb);
  k_lin<<<dim3(25, BB), 256, 0, stream>>>(Yb, x, D, m, gate, Wt + 0*FF*CC, b0, H);
  k_score<<<dim3(NN, BB), 64, 0, stream>>>(H, p0, pn + 0, ysc);
  k_pool<<<dim3(4, BB), 256, 0, stream>>>(ysc, m, ncur + 0*BB, ncur + 1*BB, gate);

  // ---- stage 2: H -> H (in-place safe: each k_lin block reads only rows it writes) ----
  k_deg<<<dim3(4, BB), 256, 0, stream>>>(idx, cnt, m, D);
  k_agg<<<BB*NN, 128, 0, stream>>>(idx, cnt, D, gate, m, H, Yb);
  k_lin<<<dim3(25, BB), 256, 0, stream>>>(Yb, H, D, m, gate, Wt + 1*FF*CC, b1, H);
  k_score<<<dim3(NN, BB), 64, 0, stream>>>(H, p1, pn + 1, ysc);
  k_pool<<<dim3(4, BB), 256, 0, stream>>>(ysc, m, ncur + 1*BB, ncur + 2*BB, gate);

  // ---- stage 3: H -> H ----
  k_deg<<<dim3(4, BB), 256, 0, stream>>>(idx, cnt, m, D);
  k_agg<<<BB*NN, 128, 0, stream>>>(idx, cnt, D, gate, m, H, Yb);
  k_lin<<<dim3(25, BB), 256, 0, stream>>>(Yb, H, D, m, gate, Wt + 2*FF*CC, b2, H);

  // ---- global max pool + FC ----
  k_fmax<<<dim3(8, BB), 128, 0, stream>>>(H, m, part);
  k_fc<<<BB, 128, 0, stream>>>(part, Wfc, bfc, out);
}

// Round 7
// 512.945 us; speedup vs baseline: 4.0928x; 1.1741x over previous
//
#include <hip/hip_runtime.h>
#include <math.h>

#define BB 32
#define NN 1000
#define CC 128
#define FF 128
#define OO 64
#define CAP 128
#define NB 40

// exact replica of JAX's np.float32(1.0 - 0.8) = 0.20000000298023224f
#define RMC ((float)(1.0 - 0.8))

// ---------------- pre: init mask/gate/ncur/pnorm + transpose the three W's ----------------
__global__ void k_pre(const float* __restrict__ mask, const int* __restrict__ Nn,
                      const float* __restrict__ p0, const float* __restrict__ p1,
                      const float* __restrict__ W0, const float* __restrict__ W1,
                      const float* __restrict__ W2,
                      float* __restrict__ m, int* __restrict__ ncur0,
                      float* __restrict__ pn, float* __restrict__ gate,
                      float* __restrict__ Wt){
  int blk = blockIdx.x, tid = threadIdx.x;
  if (blk == 3){
    for (int i = tid; i < BB*NN; i += 256){ float v = mask[i]; m[i] = v; gate[i] = v; }
    if (tid < BB) ncur0[tid] = Nn[tid];
    if (tid == 64){ float s=0.f; for(int c=0;c<FF;c++) s += p0[c]*p0[c]; pn[0] = sqrtf(s); }
    if (tid == 65){ float s=0.f; for(int c=0;c<FF;c++) s += p1[c]*p1[c]; pn[1] = sqrtf(s); }
  } else {
    const float* W = (blk == 0) ? W0 : (blk == 1) ? W1 : W2;
    float* T = Wt + (size_t)blk*FF*CC;
    for (int e = tid; e < FF*CC; e += 256){
      int c = e >> 7, f = e & 127;
      T[e] = W[f*CC + c];
    }
  }
}

// ---------------- CSR build (A is 0/1, symmetric, pre-masked), float4 scan ----------------
__global__ void k_csr(const float* __restrict__ A, short* __restrict__ idx,
                      int* __restrict__ cnt){
  int i = blockIdx.x, b = blockIdx.y, lane = threadIdx.x;   // block = 64 (one wave)
  const float4* row = (const float4*)(A + ((size_t)b*NN + i)*NN);
  short* out = idx + ((size_t)b*NN + i)*CAP;
  int count = 0;
  for (int base = 0; base < 250; base += 64){               // 1000 = 250 float4
    int q = base + lane;
    float4 v;
    if (q < 250) v = row[q]; else { v.x=v.y=v.z=v.w=0.f; }
    int lc = (v.x!=0.f) + (v.y!=0.f) + (v.z!=0.f) + (v.w!=0.f);
    int pre = lc;
    #pragma unroll
    for (int off = 1; off < 64; off <<= 1){
      int t = __shfl_up(pre, off);
      if (lane >= off) pre += t;
    }
    int tot = __shfl(pre, 63);
    pre -= lc;                                              // exclusive prefix
    int slot = count + pre;
    int j = q*4;
    if (v.x!=0.f && slot < CAP) out[slot++] = (short)j;
    if (v.y!=0.f && slot < CAP) out[slot++] = (short)(j+1);
    if (v.z!=0.f && slot < CAP) out[slot++] = (short)(j+2);
    if (v.w!=0.f && slot < CAP) out[slot++] = (short)(j+3);
    count += tot;
  }
  if (lane == 0) cnt[b*NN + i] = (count < CAP) ? count : CAP;
}

// ---------------- degree -> D = (1 + sum_nbr m_j + 1e-5)^-1/2 ----------------
__global__ void k_deg(const short* __restrict__ idx, const int* __restrict__ cnt,
                      const float* __restrict__ m, float* __restrict__ D){
  __shared__ float ml[NN];
  int b = blockIdx.y, tid = threadIdx.x;   // grid (4, BB), block = 256
  for (int i = tid; i < NN; i += 256) ml[i] = m[b*NN + i];
  __syncthreads();
  int j = blockIdx.x*250 + tid;
  if (tid < 250){
    const short* r = idx + ((size_t)b*NN + j)*CAP;
    int n = cnt[b*NN + j];
    float s0=0.f, s1=0.f, s2=0.f, s3=0.f;
    int k = 0;
    for (; k+4 <= n; k += 4){
      s0 += ml[r[k]]; s1 += ml[r[k+1]]; s2 += ml[r[k+2]]; s3 += ml[r[k+3]];
    }
    for (; k < n; k++) s0 += ml[r[k]];
    D[b*NN + j] = 1.0f / sqrtf(((s0+s1)+(s2+s3)) + 1.0f + 1e-5f);
  }
}

// ---------------- Y_i = sum_{j in nbr(i)} D_j*gate_j*h_j ----------------
// Branch-free 8-deep pipelined gather: R6's per-edge `if(d!=0)` guards forced one
// load in flight (load inside branch -> vmcnt(0) serialization); 80 µs latency-bound.
// Unconditional FMA (0-contribution is exact) lets 8 loads overlap.
__global__ void k_agg(const short* __restrict__ idx, const int* __restrict__ cnt,
                      const float* __restrict__ D, const float* __restrict__ gate,
                      const float* __restrict__ m,
                      const float* __restrict__ h, float* __restrict__ Y){
  __shared__ int   nb[CAP];                // precomputed row offsets j*CC
  __shared__ float dn[CAP];
  int blk = blockIdx.x;                    // XCD swizzle: same b lands on same XCD
  int b = (blk & 7) + 8*((blk >> 3) & 3);
  int i = blk >> 5;
  if (m[b*NN + i] == 0.f) return;          // masked target: Y never used (t *= m_i = 0)
  int c = threadIdx.x;                     // block = 128
  int n = cnt[b*NN + i];
  int np = (n + 7) & ~7;                   // pad to multiple of 8 (CAP=128 safe)
  const short* r = idx + ((size_t)b*NN + i)*CAP;
  for (int k = c; k < np; k += 128){
    int j = (k < n) ? (int)r[k] : 0;
    nb[k] = j*CC;
    dn[k] = (k < n) ? D[b*NN + j] * gate[b*NN + j] : 0.f;
  }
  __syncthreads();
  float a0=0.f,a1=0.f,a2=0.f,a3=0.f,a4=0.f,a5=0.f,a6=0.f,a7=0.f;
  const float* hb = h + (size_t)b*NN*CC;
  for (int k = 0; k < np; k += 8){
    float v0 = hb[nb[k+0] + c];
    float v1 = hb[nb[k+1] + c];
    float v2 = hb[nb[k+2] + c];
    float v3 = hb[nb[k+3] + c];
    float v4 = hb[nb[k+4] + c];
    float v5 = hb[nb[k+5] + c];
    float v6 = hb[nb[k+6] + c];
    float v7 = hb[nb[k+7] + c];
    a0 += dn[k+0]*v0; a1 += dn[k+1]*v1;
    a2 += dn[k+2]*v2; a3 += dn[k+3]*v3;
    a4 += dn[k+4]*v4; a5 += dn[k+5]*v5;
    a6 += dn[k+6]*v6; a7 += dn[k+7]*v7;
  }
  Y[((size_t)b*NN + i)*CC + c] = ((a0+a1)+(a2+a3)) + ((a4+a5)+(a6+a7));
}

// ---- t = D*(m*Y) + D^2*(gate*h) ; H = relu(t @ W^T + b)*m ----
// NOTE: exact R3 body. DO NOT add __launch_bounds__, epilogue fusion, or extra LDS:
// both decorated variants (R4 k_stage, R5 k_lin) crossed a VGPR occupancy step and
// spilled the hot loop (VGPR 64/128, ~1.5 GB phantom HBM traffic, ~590 µs vs <75 µs).
__global__ void k_lin(const float* __restrict__ Y, const float* __restrict__ h,
                      const float* __restrict__ Dv, const float* __restrict__ m,
                      const float* __restrict__ gate,
                      const float* __restrict__ Wt,   // [cc][f] transposed
                      const float* __restrict__ bias, float* __restrict__ Hout){
  __shared__ float t[NB][CC];              // 20.5 KB
  int b = blockIdx.y, tid = threadIdx.x;   // block = 256
  int i0 = blockIdx.x * NB;
  for (int e = tid; e < NB*CC; e += 256){
    int n = e >> 7, c = e & 127;
    int i = i0 + n;
    float Di = Dv[b*NN + i], mi = m[b*NN + i], gi = gate[b*NN + i];
    size_t o = ((size_t)b*NN + i)*CC + c;
    t[n][c] = Di*(mi*Y[o]) + Di*Di*(gi*h[o]);
  }
  __syncthreads();
  int fg = tid & 31;                       // 4 consecutive f per thread
  int nr = tid >> 5;                       // 0..7 node-row
  float acc[5][4];
  float4 bi = ((const float4*)bias)[fg];
  #pragma unroll
  for (int n5 = 0; n5 < 5; n5++){
    acc[n5][0]=bi.x; acc[n5][1]=bi.y; acc[n5][2]=bi.z; acc[n5][3]=bi.w;
  }
  for (int c4 = 0; c4 < 32; c4++){
    float4 tv[5];
    #pragma unroll
    for (int n5 = 0; n5 < 5; n5++)
      tv[n5] = *((const float4*)&t[nr + n5*8][c4*4]);
    #pragma unroll
    for (int k = 0; k < 4; k++){
      float4 wv = ((const float4*)Wt)[(size_t)(c4*4 + k)*32 + fg];
      #pragma unroll
      for (int n5 = 0; n5 < 5; n5++){
        float tvv = (k==0) ? tv[n5].x : (k==1) ? tv[n5].y : (k==2) ? tv[n5].z : tv[n5].w;
        acc[n5][0] += tvv*wv.x; acc[n5][1] += tvv*wv.y;
        acc[n5][2] += tvv*wv.z; acc[n5][3] += tvv*wv.w;
      }
    }
  }
  #pragma unroll
  for (int n5 = 0; n5 < 5; n5++){
    int i = i0 + nr + n5*8;
    float mi = m[b*NN + i];
    float4 o4;
    o4.x = fmaxf(acc[n5][0], 0.f)*mi;
    o4.y = fmaxf(acc[n5][1], 0.f)*mi;
    o4.z = fmaxf(acc[n5][2], 0.f)*mi;
    o4.w = fmaxf(acc[n5][3], 0.f)*mi;
    ((float4*)&Hout[((size_t)b*NN + i)*CC])[fg] = o4;
  }
}

// ---------------- pool scores y_i = (H_i . p) / |p| ----------------
__global__ void k_score(const float* __restrict__ H, const float* __restrict__ p,
                        const float* __restrict__ pn, float* __restrict__ y){
  int i = blockIdx.x, b = blockIdx.y, lane = threadIdx.x;  // block = 64
  const float* hrow = H + ((size_t)b*NN + i)*CC;
  float s = hrow[lane]*p[lane] + hrow[lane+64]*p[lane+64];
  for (int off = 32; off > 0; off >>= 1) s += __shfl_down(s, off);
  if (lane == 0) y[b*NN + i] = s / pn[0];
}

// ---------------- top-k pool: 1 node/thread, float4 LDS scan, ping-pong ncur ----------------
__global__ void k_pool(const float* __restrict__ y, float* __restrict__ m,
                       const int* __restrict__ ncur_in, int* __restrict__ ncur_out,
                       float* __restrict__ gate){
  __shared__ float yk[NN];
  int b = blockIdx.y, tid = threadIdx.x;   // grid (4, BB), block = 256
  int i = blockIdx.x*256 + tid;
  for (int j = tid; j < NN; j += 256)
    yk[j] = (m[b*NN + j] > 0.f) ? y[b*NN + j] : INFINITY;
  __syncthreads();
  int n = ncur_in[b];
  int nr = (int)((float)n * RMC);          // exact JAX semantics (f32 mult, trunc)
  float myv = (i < NN) ? yk[i] : INFINITY;
  int cnt = 0;
  const float4* yk4 = (const float4*)yk;   // broadcast reads: conflict-free
  #pragma unroll 5
  for (int q = 0; q < 250; q++){
    float4 v = yk4[q];
    int j0 = q*4;
    cnt += (int)((v.x < myv) || (v.x == myv && j0     < i));
    cnt += (int)((v.y < myv) || (v.y == myv && j0 + 1 < i));
    cnt += (int)((v.z < myv) || (v.z == myv && j0 + 2 < i));
    cnt += (int)((v.w < myv) || (v.w == myv && j0 + 3 < i));
  }
  if (i < NN){
    bool keep = (cnt >= nr) && (m[b*NN + i] > 0.f);
    m[b*NN + i]    = keep ? 1.0f : 0.0f;
    gate[b*NN + i] = keep ? tanhf(y[b*NN + i]) : 0.0f;
  }
  if (blockIdx.x == 0 && tid == 0) ncur_out[b] = n - nr;
}

// ---------------- partial global max pool (masked rows skipped; relu => max>=0) ----------------
__global__ void k_fmax(const float* __restrict__ H, const float* __restrict__ m,
                       float* __restrict__ part){
  int sx = blockIdx.x, b = blockIdx.y, c = threadIdx.x;   // grid (8, BB), block = 128
  float mx = 0.f;
  int i0 = sx*125;
  for (int i = i0; i < i0+125; i++){
    if (m[b*NN + i] != 0.f)
      mx = fmaxf(mx, H[((size_t)b*NN + i)*CC + c]);
  }
  part[((size_t)b*8 + sx)*CC + c] = mx;
}

// ---------------- combine partial maxima + FC ----------------
__global__ void k_fc(const float* __restrict__ part, const float* __restrict__ Wfc,
                     const float* __restrict__ bfc, float* __restrict__ out){
  __shared__ float g[FF];
  int b = blockIdx.x, tid = threadIdx.x;   // block = 128
  float mx = 0.f;
  #pragma unroll
  for (int s = 0; s < 8; s++) mx = fmaxf(mx, part[((size_t)b*8 + s)*CC + tid]);
  g[tid] = mx;
  __syncthreads();
  if (tid < OO){
    float acc = bfc[tid];
    for (int c = 0; c < FF; c++) acc += g[c]*Wfc[tid*FF + c];
    out[b*OO + tid] = acc;
  }
}

extern "C" void kernel_launch(void* const* d_in, const int* in_sizes, int n_in,
                              void* d_out, int out_size, void* d_ws, size_t ws_size,
                              hipStream_t stream) {
  const float* x    = (const float*)d_in[0];
  const float* A    = (const float*)d_in[1];
  const float* mask = (const float*)d_in[2];
  const int*   Nn   = (const int*)  d_in[3];
  const float* W0   = (const float*)d_in[4];
  const float* b0   = (const float*)d_in[5];
  const float* W1   = (const float*)d_in[6];
  const float* b1   = (const float*)d_in[7];
  const float* W2   = (const float*)d_in[8];
  const float* b2   = (const float*)d_in[9];
  const float* p0   = (const float*)d_in[10];
  const float* p1   = (const float*)d_in[11];
  const float* Wfc  = (const float*)d_in[12];
  const float* bfc  = (const float*)d_in[13];
  float* out = (float*)d_out;

  // workspace carve (~42 MB)
  char* w = (char*)d_ws;
  float* H   = (float*)w; w += (size_t)BB*NN*CC*4;      // 16.38 MB
  float* Yb  = (float*)w; w += (size_t)BB*NN*CC*4;      // 16.38 MB
  short* idx = (short*)w; w += (size_t)BB*NN*CAP*2;     // 8.19 MB
  float* Wt  = (float*)w; w += (size_t)3*FF*CC*4;       // 192 KB
  float* part= (float*)w; w += (size_t)8*BB*CC*4;       // 131 KB
  int*   cnt = (int*)w;   w += (size_t)BB*NN*4;
  float* D   = (float*)w; w += (size_t)BB*NN*4;
  float* m   = (float*)w; w += (size_t)BB*NN*4;
  float* ysc = (float*)w; w += (size_t)BB*NN*4;
  float* gate= (float*)w; w += (size_t)BB*NN*4;
  int*   ncur= (int*)w;   w += 3*BB*sizeof(int);        // ping-pong slots
  float* pn  = (float*)w; w += 64;

  k_pre<<<4, 256, 0, stream>>>(mask, Nn, p0, p1, W0, W1, W2, m, ncur, pn, gate, Wt);
  k_csr<<<dim3(NN, BB), 64, 0, stream>>>(A, idx, cnt);

  // ---- stage 1: x -> H ----
  k_deg<<<dim3(4, BB), 256, 0, stream>>>(idx, cnt, m, D);
  k_agg<<<BB*NN, 128, 0, stream>>>(idx, cnt, D, gate, m, x, Yb);
  k_lin<<<dim3(25, BB), 256, 0, stream>>>(Yb, x, D, m, gate, Wt + 0*FF*CC, b0, H);
  k_score<<<dim3(NN, BB), 64, 0, stream>>>(H, p0, pn + 0, ysc);
  k_pool<<<dim3(4, BB), 256, 0, stream>>>(ysc, m, ncur + 0*BB, ncur + 1*BB, gate);

  // ---- stage 2: H -> H (in-place safe: each k_lin block reads only rows it writes) ----
  k_deg<<<dim3(4, BB), 256, 0, stream>>>(idx, cnt, m, D);
  k_agg<<<BB*NN, 128, 0, stream>>>(idx, cnt, D, gate, m, H, Yb);
  k_lin<<<dim3(25, BB), 256, 0, stream>>>(Yb, H, D, m, gate, Wt + 1*FF*CC, b1, H);
  k_score<<<dim3(NN, BB), 64, 0, stream>>>(H, p1, pn + 1, ysc);
  k_pool<<<dim3(4, BB), 256, 0, stream>>>(ysc, m, ncur + 1*BB, ncur + 2*BB, gate);

  // ---- stage 3: H -> H ----
  k_deg<<<dim3(4, BB), 256, 0, stream>>>(idx, cnt, m, D);
  k_agg<<<BB*NN, 128, 0, stream>>>(idx, cnt, D, gate, m, H, Yb);
  k_lin<<<dim3(25, BB), 256, 0, stream>>>(Yb, H, D, m, gate, Wt + 2*FF*CC, b2, H);

  // ---- global max pool + FC ----
  k_fmax<<<dim3(8, BB), 128, 0, stream>>>(H, m, part);
  k_fc<<<BB, 128, 0, stream>>>(part, Wfc, bfc, out);
}